// Round 3
// baseline (214.969 us; speedup 1.0000x reference)
//
#include <hip/hip_runtime.h>

// Problem constants (fixed by setup_inputs)
#define NNODES 50000
#define NEDGES 800000
#define DIM    128
#define NRELS  4          // edge relations; weight slice 4 = self-loop
#define NBLK2  25         // scan chunks: 25*2048 = 51200 >= NNODES+1
#define NDB    1280       // dense blocks: 5 rels x 256 tile-groups (5 blocks/CU residency)
#define ILV    (2*NDB)    // dense/fill interleave window in blockIdx space
#define NFB    3125       // fill blocks
#define EPB    12500      // edges per hist chunk
#define NHC    64         // hist chunks (NHC*EPB == NEDGES)
#define RNG    25000      // dst bins per hist range-block (2 ranges cover NNODES)

typedef __attribute__((ext_vector_type(8))) short bf16x8;
typedef __attribute__((ext_vector_type(8))) unsigned short u16x8;
typedef __attribute__((ext_vector_type(4))) float f32x4;

// ---- ws layout (bytes) ----
#define SSRC_OFF 0             // u32[NEDGES]: rowcode = rel*NNODES+src, dst-sorted  3,200,000
#define CNT_OFF  3200000       // u32[51200] dst histogram excl scan                   204,800
#define BSUM_OFF 3404800       // u32[64]                                                  256
#define RANK_OFF 3405056       // u16[NEDGES] within-(chunk,dst) rank                1,600,000
#define PCNT_OFF 5005056       // u16[NHC][NNODES] per-chunk hist -> excl col-scan   6,400,000
#define WT_OFF   11405056      // bf16[5*128*128] W^T                                  163,840
#define XBF_OFF  11568896      // bf16[NNODES*DIM]                                  12,800,000
#define H_OFF    24368896      // bf16[4*NNODES*128] per-rel transforms             51,200,000
                               // total ~75.6 MB

__device__ __forceinline__ unsigned short f2bf(float f) {  // RNE f32->bf16
  unsigned u = __float_as_uint(f);
  return (unsigned short)((u + 0x7FFFu + ((u >> 16) & 1u)) >> 16);
}

// ---- prep: x f32->bf16, W transpose+convert. Pure BW, no atomics. ----
__global__ void k_prep(const float* __restrict__ x, unsigned short* __restrict__ xbf,
                       const float* __restrict__ W, unsigned short* __restrict__ Wt) {
  int i = blockIdx.x * blockDim.x + threadIdx.x;
  if (i < NNODES * DIM / 8) {
    const float4* p = (const float4*)x + i * 2;
    float4 v0 = p[0], v1 = p[1];
    u16x8 o;
    o[0] = f2bf(v0.x); o[1] = f2bf(v0.y); o[2] = f2bf(v0.z); o[3] = f2bf(v0.w);
    o[4] = f2bf(v1.x); o[5] = f2bf(v1.y); o[6] = f2bf(v1.z); o[7] = f2bf(v1.w);
    *(u16x8*)(xbf + i * 8) = o;
  }
  if (i < 5 * DIM * DIM) {
    int r = i >> 14, rem = i & 16383, k = rem >> 7, c = rem & 127;
    Wt[(r << 14) + (c << 7) + k] = f2bf(W[i]);
  }
}

// ---- LDS-privatized per-chunk dst histogram + within-chunk rank (no global atomics).
// Grid = NHC chunks x 2 dst-ranges. 25000 bins/range packed 2 x u16 per u32 = 50KB LDS.
// Low field max 12500 so the packed add never carries across fields.
__global__ __launch_bounds__(1024) void k_hist(const int* __restrict__ dst,
                                               unsigned short* __restrict__ rank,
                                               unsigned short* __restrict__ pcnt) {
  __shared__ unsigned lh[RNG / 2];  // 12500 u32 = 50,000 B
  int c = blockIdx.x >> 1;
  int r0 = (blockIdx.x & 1) * RNG;
  for (int i = threadIdx.x; i < RNG / 2; i += 1024) lh[i] = 0u;
  __syncthreads();
  int e0 = c * EPB;
  for (int e = e0 + threadIdx.x; e < e0 + EPB; e += 1024) {
    int d = dst[e] - r0;
    if ((unsigned)d < (unsigned)RNG) {
      unsigned old = atomicAdd(&lh[d >> 1], (d & 1) ? 65536u : 1u);
      rank[e] = (unsigned short)((old >> ((d & 1) << 4)) & 0xFFFFu);
    }
  }
  __syncthreads();
  // dump packed u16 pairs: exactly the u16[RNG] slice of row c at offset r0
  unsigned* prow = (unsigned*)(pcnt + (size_t)c * NNODES + r0);
  for (int i = threadIdx.x; i < RNG / 2; i += 1024) prow[i] = lh[i];
}

// ---- fused column-scan (over NHC chunk rows, in place -> exclusive chunk prefix)
// + block-local exclusive scan of the resulting totals into cnt. ----
__global__ void k_scanB(unsigned short* __restrict__ pcnt, unsigned* __restrict__ cnt,
                        unsigned* __restrict__ bsum) {
  __shared__ unsigned sh[256];
  int tid = threadIdx.x;
  int bin0 = blockIdx.x * 2048 + tid * 8;  // 8 consecutive bins per thread
  unsigned run[8] = {0, 0, 0, 0, 0, 0, 0, 0};
  if (bin0 < NNODES) {  // NNODES % 8 == 0: no straddle
    for (int b = 0; b < NHC; b++) {
      size_t off = (size_t)b * NNODES + bin0;
      u16x8 v = *(const u16x8*)(pcnt + off);
      u16x8 w;
#pragma unroll
      for (int j = 0; j < 8; j++) { w[j] = (unsigned short)run[j]; run[j] += v[j]; }
      *(u16x8*)(pcnt + off) = w;
    }
  }
  unsigned tsum = 0;
#pragma unroll
  for (int j = 0; j < 8; j++) tsum += run[j];
  sh[tid] = tsum;
  __syncthreads();
  for (int off = 1; off < 256; off <<= 1) {
    unsigned t = (tid >= off) ? sh[tid - off] : 0u;
    __syncthreads();
    sh[tid] += t;
    __syncthreads();
  }
  unsigned r = sh[tid] - tsum;
#pragma unroll
  for (int j = 0; j < 8; j++) { unsigned t = run[j]; cnt[bin0 + j] = r; r += t; }
  if (tid == 255) bsum[blockIdx.x] = sh[255];
}

// ---- add block-prefix (<=24 serial adds per block) ----
__global__ void k_fix(unsigned* __restrict__ cnt, const unsigned* __restrict__ bsum) {
  int blk = blockIdx.x;
  if (blk == 0) return;
  unsigned p = 0;
  for (int k = 0; k < blk; k++) p += bsum[k];
  int base = blk * 2048 + threadIdx.x * 8;
#pragma unroll
  for (int j = 0; j < 8; j++) cnt[base + j] += p;
}

// ---- FUSED dense + fill, interleaved in blockIdx space so both roles co-run:
// even b < ILV -> dense block di = b>>1; odd b < ILV and b >= ILV -> fill.
// Dense: di -> rel = di%5 (adjacent blocks do same x-tiles for different rels ->
// temporally coincident xbf reads, L2/LLC-served), tile-group = di/5 of 256.
// Fill: scatter edge rowcodes into dst-sorted ssrc via
// pos = cnt[d] + chunk_prefix[e/EPB][d] + within_chunk_rank[e]. No atomics anywhere.
__global__ __launch_bounds__(256, 2) void k_dfill(
    const unsigned short* __restrict__ xbf, const unsigned short* __restrict__ Wt,
    const float* __restrict__ bias, unsigned short* __restrict__ H,
    float* __restrict__ out, const int* __restrict__ rel, const int* __restrict__ dst,
    const int* __restrict__ src, const unsigned* __restrict__ cnt,
    const unsigned short* __restrict__ rank, const unsigned short* __restrict__ pfx,
    unsigned* __restrict__ ssrc) {
  int b = blockIdx.x;
  if (b >= ILV || (b & 1)) {
    // ---- fill part: pure streaming, no atomics ----
    int fi = (b < ILV) ? (b >> 1) : (b - NDB);
    int e = fi * 256 + threadIdx.x;
    if (e < NEDGES) {
      int r = rel[e]; r = r < 0 ? 0 : (r > NRELS - 1 ? NRELS - 1 : r);
      int d = dst[e];
      unsigned pos = cnt[d] + (unsigned)pfx[(size_t)(e / EPB) * NNODES + d] + (unsigned)rank[e];
      ssrc[pos] = (unsigned)(r * NNODES + src[e]);
    }
    return;
  }
  // ---- dense part ----
  __shared__ unsigned short st[4][2048];  // 4 waves x 4 KB tile staging
  int di = b >> 1;
  int lane = threadIdx.x & 63;
  int wv = threadIdx.x >> 6;
  int r = di % 5;                         // rel region 0..4
  int tl = di / 5;                        // tile-group 0..255
  const int NT = NNODES / 16;             // 3125 row-tiles per rel
  int col = lane & 15, quad = lane >> 4;

  const unsigned short* wr = Wt + (r << 14);
  bf16x8 B[8][4];
  float bs[8];
#pragma unroll
  for (int ct = 0; ct < 8; ct++) {
#pragma unroll
    for (int kk = 0; kk < 4; kk++)
      B[ct][kk] = *(const bf16x8*)(wr + ((ct * 16 + col) << 7) + kk * 32 + quad * 8);
    bs[ct] = bias[(r << 7) + ct * 16 + col];
  }

  for (int t = tl * 4 + wv; t < NT; t += 1024) {
    int n0 = t * 16;
    int na = n0 + col;
    bf16x8 a0 = *(const bf16x8*)(xbf + (na << 7) + quad * 8);
    bf16x8 a1 = *(const bf16x8*)(xbf + (na << 7) + 32 + quad * 8);
    bf16x8 a2 = *(const bf16x8*)(xbf + (na << 7) + 64 + quad * 8);
    bf16x8 a3 = *(const bf16x8*)(xbf + (na << 7) + 96 + quad * 8);

    if (r < NRELS) {
#pragma unroll
      for (int ct = 0; ct < 8; ct++) {
        f32x4 acc = {0.f, 0.f, 0.f, 0.f};
        acc = __builtin_amdgcn_mfma_f32_16x16x32_bf16(a0, B[ct][0], acc, 0, 0, 0);
        acc = __builtin_amdgcn_mfma_f32_16x16x32_bf16(a1, B[ct][1], acc, 0, 0, 0);
        acc = __builtin_amdgcn_mfma_f32_16x16x32_bf16(a2, B[ct][2], acc, 0, 0, 0);
        acc = __builtin_amdgcn_mfma_f32_16x16x32_bf16(a3, B[ct][3], acc, 0, 0, 0);
        int cc = ct * 16 + col;
#pragma unroll
        for (int j = 0; j < 4; j++) st[wv][(quad * 4 + j) * 128 + cc] = f2bf(acc[j] + bs[ct]);
      }
      // wave-private LDS round-trip (intra-wave lgkmcnt ordering; no __syncthreads)
      unsigned short* gb = H + (((size_t)(r * NNODES + n0)) << 7);
#pragma unroll
      for (int s = 0; s < 4; s++) {
        int off = s * 512 + lane * 8;  // u16 units: 4 bursts of 1KB, 16B/lane
        *(u16x8*)(gb + off) = *(const u16x8*)(&st[wv][off]);
      }
    } else {
#pragma unroll
      for (int ct = 0; ct < 8; ct++) {
        f32x4 acc = {0.f, 0.f, 0.f, 0.f};
        acc = __builtin_amdgcn_mfma_f32_16x16x32_bf16(a0, B[ct][0], acc, 0, 0, 0);
        acc = __builtin_amdgcn_mfma_f32_16x16x32_bf16(a1, B[ct][1], acc, 0, 0, 0);
        acc = __builtin_amdgcn_mfma_f32_16x16x32_bf16(a2, B[ct][2], acc, 0, 0, 0);
        acc = __builtin_amdgcn_mfma_f32_16x16x32_bf16(a3, B[ct][3], acc, 0, 0, 0);
        int cc = ct * 16 + col;
#pragma unroll
        for (int j = 0; j < 4; j++)
          out[((size_t)(n0 + quad * 4 + j) << 7) + (unsigned)cc] = acc[j] + bs[ct];
      }
    }
  }
}

// ---- segment-max over H rows per dst node + combine into d_out (RMW) ----
// Quarter-wave (16 lanes) per node; each lane owns 8 cols (uint4 = 16B of the 256B
// bf16 row). 4-row unroll -> 16 row-gathers in flight per wave, 1KB per load inst.
__global__ __launch_bounds__(256, 4) void k_agg(
    const unsigned* __restrict__ cnt, const unsigned* __restrict__ ssrc,
    const uint4* __restrict__ H4, float* __restrict__ out) {
  int lane = threadIdx.x & 15;
  int q = threadIdx.x >> 4;
  int n = blockIdx.x * 16 + q;            // grid 3125*16 = 50000 exact
  unsigned base = cnt[n];
  int deg = (int)(cnt[n + 1] - base);

  float m0 = -3.0e38f, m1 = -3.0e38f, m2 = -3.0e38f, m3 = -3.0e38f;
  float m4 = -3.0e38f, m5 = -3.0e38f, m6 = -3.0e38f, m7 = -3.0e38f;
#define UNP(v)                                        \
  m0 = fmaxf(m0, __uint_as_float((v).x << 16));       \
  m1 = fmaxf(m1, __uint_as_float((v).x & 0xFFFF0000u)); \
  m2 = fmaxf(m2, __uint_as_float((v).y << 16));       \
  m3 = fmaxf(m3, __uint_as_float((v).y & 0xFFFF0000u)); \
  m4 = fmaxf(m4, __uint_as_float((v).z << 16));       \
  m5 = fmaxf(m5, __uint_as_float((v).z & 0xFFFF0000u)); \
  m6 = fmaxf(m6, __uint_as_float((v).w << 16));       \
  m7 = fmaxf(m7, __uint_as_float((v).w & 0xFFFF0000u))
  int i = 0;
  for (; i + 4 <= deg; i += 4) {
    unsigned c0 = ssrc[base + i], c1 = ssrc[base + i + 1];
    unsigned c2 = ssrc[base + i + 2], c3 = ssrc[base + i + 3];
    uint4 v0 = H4[((size_t)c0 << 4) + lane];
    uint4 v1 = H4[((size_t)c1 << 4) + lane];
    uint4 v2 = H4[((size_t)c2 << 4) + lane];
    uint4 v3 = H4[((size_t)c3 << 4) + lane];
    UNP(v0); UNP(v1); UNP(v2); UNP(v3);
  }
  for (; i < deg; i++) {
    unsigned c = ssrc[base + i];
    uint4 v = H4[((size_t)c << 4) + lane];
    UNP(v);
  }
#undef UNP
  float4* op = (float4*)(out + ((size_t)n << 7)) + lane * 2;
  float4 s0 = op[0], s1 = op[1];          // self-loop result from k_dfill
  if (deg > 0) {                          // deg==0: DGL zero-fill, add nothing
    s0.x += m0; s0.y += m1; s0.z += m2; s0.w += m3;
    s1.x += m4; s1.y += m5; s1.z += m6; s1.w += m7;
  }
  op[0] = s0; op[1] = s1;
}

extern "C" void kernel_launch(void* const* d_in, const int* in_sizes, int n_in,
                              void* d_out, int out_size, void* d_ws, size_t ws_size,
                              hipStream_t stream) {
  const float* x = (const float*)d_in[0];
  const float* W = (const float*)d_in[1];
  const float* bias = (const float*)d_in[2];
  const int* src = (const int*)d_in[3];
  const int* dst = (const int*)d_in[4];
  const int* rel = (const int*)d_in[5];

  char* ws = (char*)d_ws;
  unsigned* ssrc = (unsigned*)(ws + SSRC_OFF);
  unsigned* cnt = (unsigned*)(ws + CNT_OFF);
  unsigned* bsum = (unsigned*)(ws + BSUM_OFF);
  unsigned short* rank = (unsigned short*)(ws + RANK_OFF);
  unsigned short* pcnt = (unsigned short*)(ws + PCNT_OFF);
  unsigned short* Wt = (unsigned short*)(ws + WT_OFF);
  unsigned short* xbf = (unsigned short*)(ws + XBF_OFF);
  unsigned short* H = (unsigned short*)(ws + H_OFF);
  float* out = (float*)d_out;

  // no memset needed: k_scanB writes every cnt entry, k_hist writes every pcnt entry
  hipLaunchKernelGGL(k_prep, dim3(3125), dim3(256), 0, stream, x, xbf, W, Wt);
  hipLaunchKernelGGL(k_hist, dim3(NHC * 2), dim3(1024), 0, stream, dst, rank, pcnt);
  hipLaunchKernelGGL(k_scanB, dim3(NBLK2), dim3(256), 0, stream, pcnt, cnt, bsum);
  hipLaunchKernelGGL(k_fix, dim3(NBLK2), dim3(256), 0, stream, cnt, bsum);
  hipLaunchKernelGGL(k_dfill, dim3(NDB + NFB), dim3(256), 0, stream, xbf, Wt, bias, H, out, rel,
                     dst, src, cnt, rank, pcnt, ssrc);
  hipLaunchKernelGGL(k_agg, dim3(3125), dim3(256), 0, stream, cnt, ssrc, (const uint4*)H, out);
}

// Round 4
// 180.077 us; speedup vs baseline: 1.1938x; 1.1938x over previous
//
#include <hip/hip_runtime.h>

// Problem constants (fixed by setup_inputs)
#define NNODES 50000
#define NEDGES 800000
#define DIM    128
#define NRELS  4          // edge relations; weight slice 4 = self-loop
#define NBLK2  25         // scan chunks: 25*2048 = 51200 >= NNODES+1
#define DBLK   128        // k_dfill dense blocks per rel (640 total) -- r2 mapping
#define NDB    (5*DBLK)   // 640 dense blocks
#define NFB    3125       // fill blocks
#define EPB    12500      // edges per hist chunk
#define NHC    64         // hist chunks (NHC*EPB == NEDGES)
#define RNG    25000      // dst bins per hist range-block (2 ranges cover NNODES)
#define NPB    782        // prep blocks in k_ph (782*1024 >= 800000)

typedef __attribute__((ext_vector_type(8))) short bf16x8;
typedef __attribute__((ext_vector_type(8))) unsigned short u16x8;
typedef __attribute__((ext_vector_type(4))) float f32x4;

// ---- ws layout (bytes) ----
#define SSRC_OFF 0             // u32[NEDGES]: rowcode = rel*NNODES+src, dst-sorted  3,200,000
#define CNT_OFF  3200000       // u32[51200] dst histogram excl scan                   204,800
#define BSUM_OFF 3404800       // u32[64]                                                  256
#define RANK_OFF 3405056       // u16[NEDGES] within-(chunk,dst) rank                1,600,000
#define PCNT_OFF 5005056       // u16[NHC][NNODES] per-chunk hist -> excl col-scan   6,400,000
#define WT_OFF   11405056      // bf16[5*128*128] W^T                                  163,840
#define XBF_OFF  11568896      // bf16[NNODES*DIM]                                  12,800,000
#define H_OFF    24368896      // bf16[4*NNODES*128] per-rel transforms             51,200,000
                               // total ~75.6 MB

__device__ __forceinline__ unsigned short f2bf(float f) {  // RNE f32->bf16
  unsigned u = __float_as_uint(f);
  return (unsigned short)((u + 0x7FFFu + ((u >> 16) & 1u)) >> 16);
}

// ---- FUSED prep + hist (independent roles, disjoint block ranges, co-scheduled):
// Blocks [0, NHC*2): LDS-privatized per-chunk dst histogram + within-chunk rank.
//   25000 bins/range packed 2 x u16 per u32 = 50KB LDS; low field max 12500 so the
//   packed add never carries across fields. No global atomics.
// Blocks [NHC*2, +NPB): x f32->bf16 convert, W transpose+convert (pure BW).
__global__ __launch_bounds__(1024) void k_ph(
    const float* __restrict__ x, unsigned short* __restrict__ xbf,
    const float* __restrict__ W, unsigned short* __restrict__ Wt,
    const int* __restrict__ dst, unsigned short* __restrict__ rank,
    unsigned short* __restrict__ pcnt) {
  __shared__ unsigned lh[RNG / 2];  // 12500 u32 = 50,000 B
  if (blockIdx.x < NHC * 2) {
    int c = blockIdx.x >> 1;
    int r0 = (blockIdx.x & 1) * RNG;
    for (int i = threadIdx.x; i < RNG / 2; i += 1024) lh[i] = 0u;
    __syncthreads();
    int e0 = c * EPB;
    for (int e = e0 + threadIdx.x; e < e0 + EPB; e += 1024) {
      int d = dst[e] - r0;
      if ((unsigned)d < (unsigned)RNG) {
        unsigned old = atomicAdd(&lh[d >> 1], (d & 1) ? 65536u : 1u);
        rank[e] = (unsigned short)((old >> ((d & 1) << 4)) & 0xFFFFu);
      }
    }
    __syncthreads();
    // dump packed u16 pairs: exactly the u16[RNG] slice of row c at offset r0
    unsigned* prow = (unsigned*)(pcnt + (size_t)c * NNODES + r0);
    for (int i = threadIdx.x; i < RNG / 2; i += 1024) prow[i] = lh[i];
    return;
  }
  int i = (blockIdx.x - NHC * 2) * 1024 + threadIdx.x;
  if (i < NNODES * DIM / 8) {
    const float4* p = (const float4*)x + i * 2;
    float4 v0 = p[0], v1 = p[1];
    u16x8 o;
    o[0] = f2bf(v0.x); o[1] = f2bf(v0.y); o[2] = f2bf(v0.z); o[3] = f2bf(v0.w);
    o[4] = f2bf(v1.x); o[5] = f2bf(v1.y); o[6] = f2bf(v1.z); o[7] = f2bf(v1.w);
    *(u16x8*)(xbf + i * 8) = o;
  }
  if (i < 5 * DIM * DIM) {
    int r = i >> 14, rem = i & 16383, k = rem >> 7, c = rem & 127;
    Wt[(r << 14) + (c << 7) + k] = f2bf(W[i]);
  }
}

// ---- fused column-scan (over NHC chunk rows, in place -> exclusive chunk prefix)
// + block-local exclusive scan of the resulting totals into cnt. ----
__global__ void k_scanB(unsigned short* __restrict__ pcnt, unsigned* __restrict__ cnt,
                        unsigned* __restrict__ bsum) {
  __shared__ unsigned sh[256];
  int tid = threadIdx.x;
  int bin0 = blockIdx.x * 2048 + tid * 8;  // 8 consecutive bins per thread
  unsigned run[8] = {0, 0, 0, 0, 0, 0, 0, 0};
  if (bin0 < NNODES) {  // NNODES % 8 == 0: no straddle
    for (int b = 0; b < NHC; b++) {
      size_t off = (size_t)b * NNODES + bin0;
      u16x8 v = *(const u16x8*)(pcnt + off);
      u16x8 w;
#pragma unroll
      for (int j = 0; j < 8; j++) { w[j] = (unsigned short)run[j]; run[j] += v[j]; }
      *(u16x8*)(pcnt + off) = w;
    }
  }
  unsigned tsum = 0;
#pragma unroll
  for (int j = 0; j < 8; j++) tsum += run[j];
  sh[tid] = tsum;
  __syncthreads();
  for (int off = 1; off < 256; off <<= 1) {
    unsigned t = (tid >= off) ? sh[tid - off] : 0u;
    __syncthreads();
    sh[tid] += t;
    __syncthreads();
  }
  unsigned r = sh[tid] - tsum;
#pragma unroll
  for (int j = 0; j < 8; j++) { unsigned t = run[j]; cnt[bin0 + j] = r; r += t; }
  if (tid == 255) bsum[blockIdx.x] = sh[255];
}

// ---- add block-prefix (<=24 serial adds per block) ----
__global__ void k_fix(unsigned* __restrict__ cnt, const unsigned* __restrict__ bsum) {
  int blk = blockIdx.x;
  if (blk == 0) return;
  unsigned p = 0;
  for (int k = 0; k < blk; k++) p += bsum[k];
  int base = blk * 2048 + threadIdx.x * 8;
#pragma unroll
  for (int j = 0; j < 8; j++) cnt[base + j] += p;
}

// ---- FUSED dense + fill (r2 mapping: dense blocks [0,NDB) then fill blocks):
// Dense: H[r][n]=xbf[n]@W_r+b_r (bf16, LDS-staged nontemporal stores); r==4 -> f32 out.
// Fill: scatter edge rowcodes into dst-sorted ssrc via
// pos = cnt[d] + chunk_prefix[e/EPB][d] + within_chunk_rank[e]. No atomics anywhere.
__global__ __launch_bounds__(256, 2) void k_dfill(
    const unsigned short* __restrict__ xbf, const unsigned short* __restrict__ Wt,
    const float* __restrict__ bias, unsigned short* __restrict__ H,
    float* __restrict__ out, const int* __restrict__ rel, const int* __restrict__ dst,
    const int* __restrict__ src, const unsigned* __restrict__ cnt,
    const unsigned short* __restrict__ rank, const unsigned short* __restrict__ pfx,
    unsigned* __restrict__ ssrc) {
  if (blockIdx.x >= NDB) {
    // ---- fill part: pure streaming, no atomics ----
    int e = (blockIdx.x - NDB) * 256 + threadIdx.x;
    if (e < NEDGES) {
      int r = rel[e]; r = r < 0 ? 0 : (r > NRELS - 1 ? NRELS - 1 : r);
      int d = dst[e];
      unsigned pos = cnt[d] + (unsigned)pfx[(size_t)(e / EPB) * NNODES + d] + (unsigned)rank[e];
      ssrc[pos] = (unsigned)(r * NNODES + src[e]);
    }
    return;
  }
  // ---- dense part ----
  __shared__ unsigned short st[4][2048];  // 4 waves x 4 KB tile staging
  int lane = threadIdx.x & 63;
  int wv = threadIdx.x >> 6;
  int r = blockIdx.x / DBLK;              // rel region 0..4
  const int NT = NNODES / 16;             // 3125 row-tiles per rel
  int col = lane & 15, quad = lane >> 4;

  const unsigned short* wr = Wt + (r << 14);
  bf16x8 B[8][4];
  float bs[8];
#pragma unroll
  for (int ct = 0; ct < 8; ct++) {
#pragma unroll
    for (int kk = 0; kk < 4; kk++)
      B[ct][kk] = *(const bf16x8*)(wr + ((ct * 16 + col) << 7) + kk * 32 + quad * 8);
    bs[ct] = bias[(r << 7) + ct * 16 + col];
  }

  for (int t = (blockIdx.x % DBLK) * 4 + wv; t < NT; t += DBLK * 4) {
    int n0 = t * 16;
    int na = n0 + col;
    bf16x8 a0 = *(const bf16x8*)(xbf + (na << 7) + quad * 8);
    bf16x8 a1 = *(const bf16x8*)(xbf + (na << 7) + 32 + quad * 8);
    bf16x8 a2 = *(const bf16x8*)(xbf + (na << 7) + 64 + quad * 8);
    bf16x8 a3 = *(const bf16x8*)(xbf + (na << 7) + 96 + quad * 8);

    if (r < NRELS) {
#pragma unroll
      for (int ct = 0; ct < 8; ct++) {
        f32x4 acc = {0.f, 0.f, 0.f, 0.f};
        acc = __builtin_amdgcn_mfma_f32_16x16x32_bf16(a0, B[ct][0], acc, 0, 0, 0);
        acc = __builtin_amdgcn_mfma_f32_16x16x32_bf16(a1, B[ct][1], acc, 0, 0, 0);
        acc = __builtin_amdgcn_mfma_f32_16x16x32_bf16(a2, B[ct][2], acc, 0, 0, 0);
        acc = __builtin_amdgcn_mfma_f32_16x16x32_bf16(a3, B[ct][3], acc, 0, 0, 0);
        int cc = ct * 16 + col;
#pragma unroll
        for (int j = 0; j < 4; j++) st[wv][(quad * 4 + j) * 128 + cc] = f2bf(acc[j] + bs[ct]);
      }
      // wave-private LDS round-trip (intra-wave lgkmcnt ordering; no __syncthreads)
      // nontemporal: H is 51MB streamed, not re-read in this kernel -> keep L2 for
      // xbf / cnt / pfx / ssrc write-merging.
      unsigned short* gb = H + (((size_t)(r * NNODES + n0)) << 7);
#pragma unroll
      for (int s = 0; s < 4; s++) {
        int off = s * 512 + lane * 8;  // u16 units: 4 bursts of 1KB, 16B/lane
        __builtin_nontemporal_store(*(const u16x8*)(&st[wv][off]), (u16x8*)(gb + off));
      }
    } else {
#pragma unroll
      for (int ct = 0; ct < 8; ct++) {
        f32x4 acc = {0.f, 0.f, 0.f, 0.f};
        acc = __builtin_amdgcn_mfma_f32_16x16x32_bf16(a0, B[ct][0], acc, 0, 0, 0);
        acc = __builtin_amdgcn_mfma_f32_16x16x32_bf16(a1, B[ct][1], acc, 0, 0, 0);
        acc = __builtin_amdgcn_mfma_f32_16x16x32_bf16(a2, B[ct][2], acc, 0, 0, 0);
        acc = __builtin_amdgcn_mfma_f32_16x16x32_bf16(a3, B[ct][3], acc, 0, 0, 0);
        int cc = ct * 16 + col;
#pragma unroll
        for (int j = 0; j < 4; j++)
          __builtin_nontemporal_store(acc[j] + bs[ct],
                                      out + ((size_t)(n0 + quad * 4 + j) << 7) + (unsigned)cc);
      }
    }
  }
}

// ---- segment-max over H rows per dst node + combine into d_out (RMW) ----
// Quarter-wave (16 lanes) per node; each lane owns 8 cols (uint4 = 16B of the 256B
// bf16 row). 8-row clamped-index batches: max is idempotent, so out-of-range rows
// clamp to the last edge (duplicate max, harmless) -> constant 8 gathers in flight,
// no serial remainder loop.
__global__ __launch_bounds__(256, 4) void k_agg(
    const unsigned* __restrict__ cnt, const unsigned* __restrict__ ssrc,
    const uint4* __restrict__ H4, float* __restrict__ out) {
  int lane = threadIdx.x & 15;
  int q = threadIdx.x >> 4;
  int n = blockIdx.x * 16 + q;            // grid 3125*16 = 50000 exact
  unsigned base = cnt[n];
  int deg = (int)(cnt[n + 1] - base);

  float m0 = -3.0e38f, m1 = -3.0e38f, m2 = -3.0e38f, m3 = -3.0e38f;
  float m4 = -3.0e38f, m5 = -3.0e38f, m6 = -3.0e38f, m7 = -3.0e38f;
#define UNP(v)                                          \
  m0 = fmaxf(m0, __uint_as_float((v).x << 16));         \
  m1 = fmaxf(m1, __uint_as_float((v).x & 0xFFFF0000u)); \
  m2 = fmaxf(m2, __uint_as_float((v).y << 16));         \
  m3 = fmaxf(m3, __uint_as_float((v).y & 0xFFFF0000u)); \
  m4 = fmaxf(m4, __uint_as_float((v).z << 16));         \
  m5 = fmaxf(m5, __uint_as_float((v).z & 0xFFFF0000u)); \
  m6 = fmaxf(m6, __uint_as_float((v).w << 16));         \
  m7 = fmaxf(m7, __uint_as_float((v).w & 0xFFFF0000u))
  if (deg > 0) {
    int lim = deg - 1;
    for (int i = 0; i < deg; i += 8) {
      unsigned c0 = ssrc[base + min(i, lim)];
      unsigned c1 = ssrc[base + min(i + 1, lim)];
      unsigned c2 = ssrc[base + min(i + 2, lim)];
      unsigned c3 = ssrc[base + min(i + 3, lim)];
      unsigned c4 = ssrc[base + min(i + 4, lim)];
      unsigned c5 = ssrc[base + min(i + 5, lim)];
      unsigned c6 = ssrc[base + min(i + 6, lim)];
      unsigned c7 = ssrc[base + min(i + 7, lim)];
      uint4 v0 = H4[((size_t)c0 << 4) + lane];
      uint4 v1 = H4[((size_t)c1 << 4) + lane];
      uint4 v2 = H4[((size_t)c2 << 4) + lane];
      uint4 v3 = H4[((size_t)c3 << 4) + lane];
      uint4 v4 = H4[((size_t)c4 << 4) + lane];
      uint4 v5 = H4[((size_t)c5 << 4) + lane];
      uint4 v6 = H4[((size_t)c6 << 4) + lane];
      uint4 v7 = H4[((size_t)c7 << 4) + lane];
      UNP(v0); UNP(v1); UNP(v2); UNP(v3);
      UNP(v4); UNP(v5); UNP(v6); UNP(v7);
    }
  }
#undef UNP
  float4* op = (float4*)(out + ((size_t)n << 7)) + lane * 2;
  float4 s0 = op[0], s1 = op[1];          // self-loop result from k_dfill
  if (deg > 0) {                          // deg==0: DGL zero-fill, add nothing
    s0.x += m0; s0.y += m1; s0.z += m2; s0.w += m3;
    s1.x += m4; s1.y += m5; s1.z += m6; s1.w += m7;
  }
  op[0] = s0; op[1] = s1;
}

extern "C" void kernel_launch(void* const* d_in, const int* in_sizes, int n_in,
                              void* d_out, int out_size, void* d_ws, size_t ws_size,
                              hipStream_t stream) {
  const float* x = (const float*)d_in[0];
  const float* W = (const float*)d_in[1];
  const float* bias = (const float*)d_in[2];
  const int* src = (const int*)d_in[3];
  const int* dst = (const int*)d_in[4];
  const int* rel = (const int*)d_in[5];

  char* ws = (char*)d_ws;
  unsigned* ssrc = (unsigned*)(ws + SSRC_OFF);
  unsigned* cnt = (unsigned*)(ws + CNT_OFF);
  unsigned* bsum = (unsigned*)(ws + BSUM_OFF);
  unsigned short* rank = (unsigned short*)(ws + RANK_OFF);
  unsigned short* pcnt = (unsigned short*)(ws + PCNT_OFF);
  unsigned short* Wt = (unsigned short*)(ws + WT_OFF);
  unsigned short* xbf = (unsigned short*)(ws + XBF_OFF);
  unsigned short* H = (unsigned short*)(ws + H_OFF);
  float* out = (float*)d_out;

  // no memset needed: k_scanB writes every cnt entry, k_ph writes every pcnt entry
  hipLaunchKernelGGL(k_ph, dim3(NHC * 2 + NPB), dim3(1024), 0, stream, x, xbf, W, Wt, dst, rank,
                     pcnt);
  hipLaunchKernelGGL(k_scanB, dim3(NBLK2), dim3(256), 0, stream, pcnt, cnt, bsum);
  hipLaunchKernelGGL(k_fix, dim3(NBLK2), dim3(256), 0, stream, cnt, bsum);
  hipLaunchKernelGGL(k_dfill, dim3(NDB + NFB), dim3(256), 0, stream, xbf, Wt, bias, H, out, rel,
                     dst, src, cnt, rank, pcnt, ssrc);
  hipLaunchKernelGGL(k_agg, dim3(3125), dim3(256), 0, stream, cnt, ssrc, (const uint4*)H, out);
}